// Round 11
// baseline (53.619 us; speedup 1.0000x reference)
//
#include <hip/hip_runtime.h>
#include <hip/hip_bf16.h>

// Problem constants (from reference): B=32, N=2048, M=16, K=32, H=in_sizes[2]
constexpr int Bc = 32;
constexpr int Nc = 2048;
constexpr int Mc = 16;
constexpr int Kc = 32;
constexpr int ROWc = 17;           // 17 floats per dgm row
constexpr int CH = 256;            // rows per staged chunk
constexpr int NCH = Nc / CH;       // 8 chunks per batch
constexpr int KQ = 8;              // k's per block (k-octet)
constexpr int NKQ = Kc / KQ;       // 4 k-octets
constexpr float EPSc = 1e-7f;
constexpr float HALF_LN2 = 0.34657359028f;   // 0.5 * ln 2

// ---------------------------------------------------------------------------
// MEASUREMENT ROUND: kernels are byte-identical to round 10 (best: 31.2 us).
// kernel_launch dispatches k_T twice and k_scan twice (idempotent rewrites of
// identical values). total = 2*(t_kT + t_scan + 2c) + F  =>  F = 62.4 - total.
// Disambiguates "fixed replay overhead dominates" vs "k_T body dominates".
// ---------------------------------------------------------------------------
__global__ __launch_bounds__(512) void k_T(const float* __restrict__ dgm,
                                           const float* __restrict__ theta,
                                           const float* __restrict__ class_w,
                                           float* __restrict__ P,
                                           int H) {
    __shared__ float stage[CH * 20];   // 20480 B: [row][20], hom@0, coords@4..19
    __shared__ float red[8 * KQ * 17]; // 4352 B: [wave][k8*17 + m] padded

    int bid = blockIdx.x;
    int b   = bid >> 5;                // bid = b*32 + kq*8 + c
    int rem = bid & 31;
    int kq  = rem >> 3;
    int c   = rem & 7;
    int tid = threadIdx.x;
    int k8  = tid & 7;
    int rg  = tid >> 3;                // 0..63 rowgroups x 4 rows

    // ---- stage 256x17 floats (1088 float4, coalesced) into padded layout ----
    const float4* src4 = (const float4*)(dgm + ((size_t)b * Nc + c * CH) * ROWc);
    for (int i = tid; i < (CH * ROWc) / 4; i += 512) {
        float4 v = src4[i];
        unsigned g = 4u * i;
#pragma unroll
        for (int e = 0; e < 4; ++e) {
            unsigned ge  = g + e;
            unsigned row = ge / 17u;
            unsigned col = ge - row * 17u;
            float val = (e == 0) ? v.x : (e == 1) ? v.y : (e == 2) ? v.z : v.w;
            stage[row * 20 + (col == 0 ? 0u : col + 3u)] = val;
        }
    }

    // ---- per-thread theta^2 for its global k = kq*8 + k8 ----
    int kg = kq * KQ + k8;
    float th2[16];
    {
        const float4* t4 = (const float4*)theta;
#pragma unroll
        for (int q = 0; q < 4; ++q) {
            float4 tv = t4[kg * 4 + q];
            th2[4*q+0] = tv.x * tv.x; th2[4*q+1] = tv.y * tv.y;
            th2[4*q+2] = tv.z * tv.z; th2[4*q+3] = tv.w * tv.w;
        }
    }
    float cw0 = class_w[0];
    float cw1 = (H > 1) ? class_w[1] : cw0;

    __syncthreads();

    // ---- accumulate 4 rows for this (k8, rowgroup) ----
    float acc[16];
#pragma unroll
    for (int m = 0; m < 16; ++m) acc[m] = 0.0f;

#pragma unroll
    for (int j = 0; j < 4; ++j) {
        int row = rg * 4 + j;
        const float* rp = &stage[row * 20];
        float r0 = rp[0];
        float r[16];
        {   // aligned float4 LDS reads, broadcast across the 8 k-lanes
            float4* rv = (float4*)r;
            const float4* lp = (const float4*)(rp + 4);
            rv[0] = lp[0]; rv[1] = lp[1]; rv[2] = lp[2]; rv[3] = lp[3];
        }

        int h = (int)r0;               // trunc == astype(int32)
        h = max(0, min(h, H - 1));
        float wv = (H == 2) ? (h ? cw1 : cw0) : class_w[h];

        float za = 0.f, zb = 0.f, zc = 0.f, zd = 0.f;   // 4 indep chains
#pragma unroll
        for (int m = 0; m < 16; m += 4) {
            za = fmaf(r[m]   * r[m],   th2[m],   za);
            zb = fmaf(r[m+1] * r[m+1], th2[m+1], zb);
            zc = fmaf(r[m+2] * r[m+2], th2[m+2], zc);
            zd = fmaf(r[m+3] * r[m+3], th2[m+3], zd);
        }
        float zn2 = (za + zb) + (zc + zd);
        float rs  = rsqrtf(fmaxf(zn2, 1e-30f));
        float zn  = zn2 * rs;                       // ||z|| (0 if zn2==0)
        float s   = sqrtf(1.0f + zn2);
        float at2 = __log2f(zn + s);
        float coef = HALF_LN2 * at2 * rs * wv;      // exactly 0 for zero rows
#pragma unroll
        for (int m = 0; m < 16; ++m) acc[m] = fmaf(coef, r[m], acc[m]);
    }

    // ---- fold the 8 rowgroups within each wave (lane bits 3,4,5) ----
#pragma unroll
    for (int m = 0; m < 16; ++m) {
        acc[m] += __shfl_xor(acc[m], 8);
        acc[m] += __shfl_xor(acc[m], 16);
        acc[m] += __shfl_xor(acc[m], 32);
    }

    int w = tid >> 6;                  // wave 0..7
    if ((tid & 63) < 8) {              // lane == k8 for these lanes
#pragma unroll
        for (int m = 0; m < 16; ++m) red[w * (KQ * 17) + k8 * 17 + m] = acc[m];
    }
    __syncthreads();

    // ---- final: one (k8,m) pair per thread; apply theta; store partial ----
    if (tid < KQ * 16) {
        int kk = tid >> 4;             // 0..7
        int mm = tid & 15;
        float s = 0.0f;
#pragma unroll
        for (int w2 = 0; w2 < 8; ++w2) s += red[w2 * (KQ * 17) + kk * 17 + mm];
        P[(size_t)bid * 128 + tid] = s * theta[kq * 128 + tid]; // theta[(kq*8+kk)*16+mm]
    }
}

// ---------------------------------------------------------------------------
// Kernel B: T[row][m] = sum_c P[b,kq,c][k8][m] (row = b*32 + k); S = cumsum
// over the 1024 flattened rows; yd = 2*xd/(1-||xd||^2),
// xd = tanh(||S||)*S/max(||S||,eps). Single block, 1024 threads.
// thread = (m = tid&15, seg = tid>>4).
// ---------------------------------------------------------------------------
__global__ __launch_bounds__(1024) void k_scan(const float* __restrict__ P,
                                               float* __restrict__ out) {
    __shared__ float buf[2][64][Mc];

    int tid = threadIdx.x;
    int m   = tid & 15;
    int seg = tid >> 4;            // 0..63, 16 rows each -> 1024 rows

    float p[16];
    float run = 0.0f;
#pragma unroll
    for (int j = 0; j < 16; ++j) {
        int row = seg * 16 + j;    // = b*32 + k
        int b   = row >> 5;
        int k   = row & 31;
        int kq  = k >> 3;
        int k8  = k & 7;
        const float* q = P + (size_t)b * 4096 + kq * 1024 + k8 * 16 + m;
        float t0 = q[0]       + q[128]     + q[2 * 128] + q[3 * 128];
        float t1 = q[4 * 128] + q[5 * 128] + q[6 * 128] + q[7 * 128];
        run += t0 + t1;
        p[j] = run;
    }

    buf[0][seg][m] = run;
    __syncthreads();
    int src = 0;
#pragma unroll
    for (int d = 1; d < 64; d <<= 1) {
        float v = buf[src][seg][m];
        if (seg >= d) v += buf[src][seg - d][m];
        buf[src ^ 1][seg][m] = v;
        __syncthreads();
        src ^= 1;
    }
    float off = (seg > 0) ? buf[src][seg - 1][m] : 0.0f;

#pragma unroll
    for (int j = 0; j < 16; ++j) {
        float S = off + p[j];
        float sn2 = S * S;
        sn2 += __shfl_xor(sn2, 1);
        sn2 += __shfl_xor(sn2, 2);
        sn2 += __shfl_xor(sn2, 4);
        sn2 += __shfl_xor(sn2, 8);
        float sn = sqrtf(sn2);
        // tanh(sn) = 1 - 2/(e^{2 sn}+1)
        float e  = __expf(2.0f * sn);
        float t  = 1.0f - 2.0f / (e + 1.0f);
        float cc = t / fmaxf(sn, EPSc);
        float sx2 = cc * cc * sn2;             // == sum(xd^2)
        float yd = 2.0f * cc * S / (1.0f - sx2);
        out[(size_t)(seg * 16 + j) * Mc + m] = yd;
    }
}

// ---------------------------------------------------------------------------
extern "C" void kernel_launch(void* const* d_in, const int* in_sizes, int n_in,
                              void* d_out, int out_size, void* d_ws, size_t ws_size,
                              hipStream_t stream) {
    const float* dgm     = (const float*)d_in[0];   // (B, N, 17)
    const float* theta   = (const float*)d_in[1];   // (K, M)
    const float* class_w = (const float*)d_in[2];   // (H,)
    int H = in_sizes[2];

    float* P   = (float*)d_ws;                      // 1024 x 128 floats = 512 KB
    float* out = (float*)d_out;

    // DOUBLED DISPATCHES (idempotent): F = 2*31.2 - total(this round)
    k_T<<<Bc * NKQ * NCH, 512, 0, stream>>>(dgm, theta, class_w, P, H);
    k_T<<<Bc * NKQ * NCH, 512, 0, stream>>>(dgm, theta, class_w, P, H);
    k_scan<<<1, 1024, 0, stream>>>(P, out);
    k_scan<<<1, 1024, 0, stream>>>(P, out);
}

// Round 12
// 30.673 us; speedup vs baseline: 1.7481x; 1.7481x over previous
//
#include <hip/hip_runtime.h>
#include <hip/hip_bf16.h>

// Problem constants (from reference): B=32, N=2048, M=16, K=32, H=in_sizes[2]
constexpr int Bc = 32;
constexpr int Nc = 2048;
constexpr int Mc = 16;
constexpr int Kc = 32;
constexpr int ROWc = 17;           // 17 floats per dgm row
constexpr int CH = 256;            // rows per staged chunk
constexpr int NCH = Nc / CH;       // 8 chunks per batch
constexpr int KQ = 8;              // k's per block (k-octet)
constexpr int NKQ = Kc / KQ;       // 4 k-octets
constexpr float EPSc = 1e-7f;
constexpr float HALF_LN2 = 0.34657359028f;   // 0.5 * ln 2

// ---------------------------------------------------------------------------
// Kernel A: identical structure to round 10 (best k_T so far). Only the
// partial-store LAYOUT changed: P[row][m][c] with the chunk index c
// CONTIGUOUS, so k_scan can reduce the 8 chunk partials with 2 float4 loads
// instead of 8 scalar 512B-strided loads. row = b*32 + kq*8 + kk.
// ---------------------------------------------------------------------------
__global__ __launch_bounds__(512) void k_T(const float* __restrict__ dgm,
                                           const float* __restrict__ theta,
                                           const float* __restrict__ class_w,
                                           float* __restrict__ P,
                                           int H) {
    __shared__ float stage[CH * 20];   // 20480 B: [row][20], hom@0, coords@4..19
    __shared__ float red[8 * KQ * 17]; // 4352 B: [wave][k8*17 + m] padded

    int bid = blockIdx.x;
    int b   = bid >> 5;                // bid = b*32 + kq*8 + c
    int rem = bid & 31;
    int kq  = rem >> 3;
    int c   = rem & 7;
    int tid = threadIdx.x;
    int k8  = tid & 7;
    int rg  = tid >> 3;                // 0..63 rowgroups x 4 rows

    // ---- stage 256x17 floats (1088 float4, coalesced) into padded layout ----
    const float4* src4 = (const float4*)(dgm + ((size_t)b * Nc + c * CH) * ROWc);
    for (int i = tid; i < (CH * ROWc) / 4; i += 512) {
        float4 v = src4[i];
        unsigned g = 4u * i;
#pragma unroll
        for (int e = 0; e < 4; ++e) {
            unsigned ge  = g + e;
            unsigned row = ge / 17u;
            unsigned col = ge - row * 17u;
            float val = (e == 0) ? v.x : (e == 1) ? v.y : (e == 2) ? v.z : v.w;
            stage[row * 20 + (col == 0 ? 0u : col + 3u)] = val;
        }
    }

    // ---- per-thread theta^2 for its global k = kq*8 + k8 ----
    int kg = kq * KQ + k8;
    float th2[16];
    {
        const float4* t4 = (const float4*)theta;
#pragma unroll
        for (int q = 0; q < 4; ++q) {
            float4 tv = t4[kg * 4 + q];
            th2[4*q+0] = tv.x * tv.x; th2[4*q+1] = tv.y * tv.y;
            th2[4*q+2] = tv.z * tv.z; th2[4*q+3] = tv.w * tv.w;
        }
    }
    float cw0 = class_w[0];
    float cw1 = (H > 1) ? class_w[1] : cw0;

    __syncthreads();

    // ---- accumulate 4 rows for this (k8, rowgroup) ----
    float acc[16];
#pragma unroll
    for (int m = 0; m < 16; ++m) acc[m] = 0.0f;

#pragma unroll
    for (int j = 0; j < 4; ++j) {
        int row = rg * 4 + j;
        const float* rp = &stage[row * 20];
        float r0 = rp[0];
        float r[16];
        {   // aligned float4 LDS reads, broadcast across the 8 k-lanes
            float4* rv = (float4*)r;
            const float4* lp = (const float4*)(rp + 4);
            rv[0] = lp[0]; rv[1] = lp[1]; rv[2] = lp[2]; rv[3] = lp[3];
        }

        int h = (int)r0;               // trunc == astype(int32)
        h = max(0, min(h, H - 1));
        float wv = (H == 2) ? (h ? cw1 : cw0) : class_w[h];

        float za = 0.f, zb = 0.f, zc = 0.f, zd = 0.f;   // 4 indep chains
#pragma unroll
        for (int m = 0; m < 16; m += 4) {
            za = fmaf(r[m]   * r[m],   th2[m],   za);
            zb = fmaf(r[m+1] * r[m+1], th2[m+1], zb);
            zc = fmaf(r[m+2] * r[m+2], th2[m+2], zc);
            zd = fmaf(r[m+3] * r[m+3], th2[m+3], zd);
        }
        float zn2 = (za + zb) + (zc + zd);
        float rs  = rsqrtf(fmaxf(zn2, 1e-30f));
        float zn  = zn2 * rs;                       // ||z|| (0 if zn2==0)
        float s   = sqrtf(1.0f + zn2);
        float at2 = __log2f(zn + s);
        float coef = HALF_LN2 * at2 * rs * wv;      // exactly 0 for zero rows
#pragma unroll
        for (int m = 0; m < 16; ++m) acc[m] = fmaf(coef, r[m], acc[m]);
    }

    // ---- fold the 8 rowgroups within each wave (lane bits 3,4,5) ----
#pragma unroll
    for (int m = 0; m < 16; ++m) {
        acc[m] += __shfl_xor(acc[m], 8);
        acc[m] += __shfl_xor(acc[m], 16);
        acc[m] += __shfl_xor(acc[m], 32);
    }

    int w = tid >> 6;                  // wave 0..7
    if ((tid & 63) < 8) {              // lane == k8 for these lanes
#pragma unroll
        for (int m = 0; m < 16; ++m) red[w * (KQ * 17) + k8 * 17 + m] = acc[m];
    }
    __syncthreads();

    // ---- final: one (k8,m) pair per thread; apply theta; store partial ----
    // NEW LAYOUT: P[((b*32 + kq*8 + kk)*16 + mm)*8 + c]  (c contiguous)
    if (tid < KQ * 16) {
        int kk = tid >> 4;             // 0..7
        int mm = tid & 15;
        float s = 0.0f;
#pragma unroll
        for (int w2 = 0; w2 < 8; ++w2) s += red[w2 * (KQ * 17) + kk * 17 + mm];
        float val = s * theta[kq * 128 + tid];      // theta[(kq*8+kk)*16+mm]
        P[((size_t)b * 4096 + (size_t)kq * 1024 + (size_t)kk * 128 + mm * 8) + c] = val;
    }
}

// ---------------------------------------------------------------------------
// Kernel B: T[row][m] = sum_c P[row][m][c] -- now TWO aligned float4 loads
// per (row,m) instead of 8 scalar 512B-strided loads. Then S = cumsum over
// the 1024 flattened rows; yd = 2*xd/(1-||xd||^2),
// xd = tanh(||S||)*S/max(||S||,eps). Single block, 1024 threads.
// thread = (m = tid&15, seg = tid>>4).
// ---------------------------------------------------------------------------
__global__ __launch_bounds__(1024) void k_scan(const float* __restrict__ P,
                                               float* __restrict__ out) {
    __shared__ float buf[2][64][Mc];

    int tid = threadIdx.x;
    int m   = tid & 15;
    int seg = tid >> 4;            // 0..63, 16 rows each -> 1024 rows

    float p[16];
    float run = 0.0f;
#pragma unroll
    for (int j = 0; j < 16; ++j) {
        int row = seg * 16 + j;    // = b*32 + k
        const float4* q = (const float4*)(P + (size_t)row * 128 + m * 8);
        float4 a = q[0];
        float4 bq = q[1];
        run += ((a.x + a.y) + (a.z + a.w)) + ((bq.x + bq.y) + (bq.z + bq.w));
        p[j] = run;
    }

    buf[0][seg][m] = run;
    __syncthreads();
    int src = 0;
#pragma unroll
    for (int d = 1; d < 64; d <<= 1) {
        float v = buf[src][seg][m];
        if (seg >= d) v += buf[src][seg - d][m];
        buf[src ^ 1][seg][m] = v;
        __syncthreads();
        src ^= 1;
    }
    float off = (seg > 0) ? buf[src][seg - 1][m] : 0.0f;

#pragma unroll
    for (int j = 0; j < 16; ++j) {
        float S = off + p[j];
        float sn2 = S * S;
        sn2 += __shfl_xor(sn2, 1);
        sn2 += __shfl_xor(sn2, 2);
        sn2 += __shfl_xor(sn2, 4);
        sn2 += __shfl_xor(sn2, 8);
        float sn = sqrtf(sn2);
        // tanh(sn) = 1 - 2/(e^{2 sn}+1)
        float e  = __expf(2.0f * sn);
        float t  = 1.0f - 2.0f / (e + 1.0f);
        float cc = t / fmaxf(sn, EPSc);
        float sx2 = cc * cc * sn2;             // == sum(xd^2)
        float yd = 2.0f * cc * S / (1.0f - sx2);
        out[(size_t)(seg * 16 + j) * Mc + m] = yd;
    }
}

// ---------------------------------------------------------------------------
extern "C" void kernel_launch(void* const* d_in, const int* in_sizes, int n_in,
                              void* d_out, int out_size, void* d_ws, size_t ws_size,
                              hipStream_t stream) {
    const float* dgm     = (const float*)d_in[0];   // (B, N, 17)
    const float* theta   = (const float*)d_in[1];   // (K, M)
    const float* class_w = (const float*)d_in[2];   // (H,)
    int H = in_sizes[2];

    float* P   = (float*)d_ws;                      // 1024 x 128 floats = 512 KB
    float* out = (float*)d_out;

    k_T<<<Bc * NKQ * NCH, 512, 0, stream>>>(dgm, theta, class_w, P, H);
    k_scan<<<1, 1024, 0, stream>>>(P, out);
}

// Round 13
// 30.007 us; speedup vs baseline: 1.7869x; 1.0222x over previous
//
#include <hip/hip_runtime.h>
#include <hip/hip_bf16.h>

// Problem constants (from reference): B=32, N=2048, M=16, K=32, H=in_sizes[2]
constexpr int Bc = 32;
constexpr int Nc = 2048;
constexpr int Mc = 16;
constexpr int Kc = 32;
constexpr int ROWc = 17;           // 17 floats per dgm row
constexpr int CH = 256;            // rows per staged chunk
constexpr int NCH = Nc / CH;       // 8 chunks per batch
constexpr int KQ = 8;              // k's per block (k-octet)
constexpr int NKQ = Kc / KQ;       // 4 k-octets
constexpr float EPSc = 1e-7f;
constexpr float HALF_LN2 = 0.34657359028f;   // 0.5 * ln 2

// ---------------------------------------------------------------------------
// Kernel A: 1024 blocks x 256 THREADS (was 512): 4 waves/block, ~5 blocks/CU
// co-resident -> the whole grid fits in ONE launch round (512-thr blocks at
// ~100 VGPR only fit 2/CU -> 2 serial rounds). Thread (k8 = tid&7,
// rg = tid>>3 in 0..31) accumulates its k over 8 broadcast-read rows.
// Math identical to r10/r12 (passed absmax 0.25-0.5):
//   T[b,k,m] = th[k][m] * sum_n coef(n,k)*y[n,m],
//   coef = 0.5*asinh(||z||)/||z|| * w    (atanh(||x||) = asinh(||z||)/2);
//   zero rows contribute exactly 0 -> no validity logic.
// P layout (r12): P[((b*32+kq*8+kk)*16+mm)*8 + c], chunk index contiguous.
// ---------------------------------------------------------------------------
__global__ __launch_bounds__(256) void k_T(const float* __restrict__ dgm,
                                           const float* __restrict__ theta,
                                           const float* __restrict__ class_w,
                                           float* __restrict__ P,
                                           int H) {
    __shared__ float stage[CH * 20];   // 20480 B: [row][20], hom@0, coords@4..19
    __shared__ float red[4 * KQ * 17]; // 2176 B: [wave][k8*17 + m] padded

    int bid = blockIdx.x;
    int b   = bid >> 5;                // bid = b*32 + kq*8 + c
    int rem = bid & 31;
    int kq  = rem >> 3;
    int c   = rem & 7;
    int tid = threadIdx.x;
    int k8  = tid & 7;
    int rg  = tid >> 3;                // 0..31 rowgroups x 8 rows

    // ---- stage 256x17 floats (1088 float4, coalesced) into padded layout ----
    const float4* src4 = (const float4*)(dgm + ((size_t)b * Nc + c * CH) * ROWc);
    for (int i = tid; i < (CH * ROWc) / 4; i += 256) {
        float4 v = src4[i];
        unsigned g = 4u * i;
#pragma unroll
        for (int e = 0; e < 4; ++e) {
            unsigned ge  = g + e;
            unsigned row = ge / 17u;
            unsigned col = ge - row * 17u;
            float val = (e == 0) ? v.x : (e == 1) ? v.y : (e == 2) ? v.z : v.w;
            stage[row * 20 + (col == 0 ? 0u : col + 3u)] = val;
        }
    }

    // ---- per-thread theta^2 for its global k = kq*8 + k8 ----
    int kg = kq * KQ + k8;
    float th2[16];
    {
        const float4* t4 = (const float4*)theta;
#pragma unroll
        for (int q = 0; q < 4; ++q) {
            float4 tv = t4[kg * 4 + q];
            th2[4*q+0] = tv.x * tv.x; th2[4*q+1] = tv.y * tv.y;
            th2[4*q+2] = tv.z * tv.z; th2[4*q+3] = tv.w * tv.w;
        }
    }
    float cw0 = class_w[0];
    float cw1 = (H > 1) ? class_w[1] : cw0;

    __syncthreads();

    // ---- accumulate 8 rows for this (k8, rowgroup) ----
    float acc[16];
#pragma unroll
    for (int m = 0; m < 16; ++m) acc[m] = 0.0f;

#pragma unroll
    for (int j = 0; j < 8; ++j) {
        int row = rg * 8 + j;
        const float* rp = &stage[row * 20];
        float r0 = rp[0];
        float r[16];
        {   // aligned float4 LDS reads, broadcast across the 8 k-lanes
            float4* rv = (float4*)r;
            const float4* lp = (const float4*)(rp + 4);
            rv[0] = lp[0]; rv[1] = lp[1]; rv[2] = lp[2]; rv[3] = lp[3];
        }

        int h = (int)r0;               // trunc == astype(int32)
        h = max(0, min(h, H - 1));
        float wv = (H == 2) ? (h ? cw1 : cw0) : class_w[h];

        float za = 0.f, zb = 0.f, zc = 0.f, zd = 0.f;   // 4 indep chains
#pragma unroll
        for (int m = 0; m < 16; m += 4) {
            za = fmaf(r[m]   * r[m],   th2[m],   za);
            zb = fmaf(r[m+1] * r[m+1], th2[m+1], zb);
            zc = fmaf(r[m+2] * r[m+2], th2[m+2], zc);
            zd = fmaf(r[m+3] * r[m+3], th2[m+3], zd);
        }
        float zn2 = (za + zb) + (zc + zd);
        float rs  = rsqrtf(fmaxf(zn2, 1e-30f));
        float zn  = zn2 * rs;                       // ||z|| (0 if zn2==0)
        float s   = sqrtf(1.0f + zn2);
        float at2 = __log2f(zn + s);
        float coef = HALF_LN2 * at2 * rs * wv;      // exactly 0 for zero rows
#pragma unroll
        for (int m = 0; m < 16; ++m) acc[m] = fmaf(coef, r[m], acc[m]);
    }

    // ---- fold the 8 rowgroups within each wave (lane bits 3,4,5) ----
#pragma unroll
    for (int m = 0; m < 16; ++m) {
        acc[m] += __shfl_xor(acc[m], 8);
        acc[m] += __shfl_xor(acc[m], 16);
        acc[m] += __shfl_xor(acc[m], 32);
    }

    int w = tid >> 6;                  // wave 0..3
    if ((tid & 63) < 8) {              // lane == k8 for these lanes
#pragma unroll
        for (int m = 0; m < 16; ++m) red[w * (KQ * 17) + k8 * 17 + m] = acc[m];
    }
    __syncthreads();

    // ---- final: one (k8,m) pair per thread; apply theta; store partial ----
    if (tid < KQ * 16) {
        int kk = tid >> 4;             // 0..7
        int mm = tid & 15;
        float s = 0.0f;
#pragma unroll
        for (int w2 = 0; w2 < 4; ++w2) s += red[w2 * (KQ * 17) + kk * 17 + mm];
        float val = s * theta[kq * 128 + tid];      // theta[(kq*8+kk)*16+mm]
        P[((size_t)b * 4096 + (size_t)kq * 1024 + (size_t)kk * 128 + mm * 8) + c] = val;
    }
}

// ---------------------------------------------------------------------------
// Kernel B (unchanged from r12): T[row][m] = sum_c P[row][m][c] via two
// aligned float4 loads; S = cumsum over the 1024 flattened rows;
// yd = 2*xd/(1-||xd||^2), xd = tanh(||S||)*S/max(||S||,eps).
// Single block, 1024 threads; thread = (m = tid&15, seg = tid>>4).
// ---------------------------------------------------------------------------
__global__ __launch_bounds__(1024) void k_scan(const float* __restrict__ P,
                                               float* __restrict__ out) {
    __shared__ float buf[2][64][Mc];

    int tid = threadIdx.x;
    int m   = tid & 15;
    int seg = tid >> 4;            // 0..63, 16 rows each -> 1024 rows

    float p[16];
    float run = 0.0f;
#pragma unroll
    for (int j = 0; j < 16; ++j) {
        int row = seg * 16 + j;    // = b*32 + k
        const float4* q = (const float4*)(P + (size_t)row * 128 + m * 8);
        float4 a = q[0];
        float4 bq = q[1];
        run += ((a.x + a.y) + (a.z + a.w)) + ((bq.x + bq.y) + (bq.z + bq.w));
        p[j] = run;
    }

    buf[0][seg][m] = run;
    __syncthreads();
    int src = 0;
#pragma unroll
    for (int d = 1; d < 64; d <<= 1) {
        float v = buf[src][seg][m];
        if (seg >= d) v += buf[src][seg - d][m];
        buf[src ^ 1][seg][m] = v;
        __syncthreads();
        src ^= 1;
    }
    float off = (seg > 0) ? buf[src][seg - 1][m] : 0.0f;

#pragma unroll
    for (int j = 0; j < 16; ++j) {
        float S = off + p[j];
        float sn2 = S * S;
        sn2 += __shfl_xor(sn2, 1);
        sn2 += __shfl_xor(sn2, 2);
        sn2 += __shfl_xor(sn2, 4);
        sn2 += __shfl_xor(sn2, 8);
        float sn = sqrtf(sn2);
        // tanh(sn) = 1 - 2/(e^{2 sn}+1)
        float e  = __expf(2.0f * sn);
        float t  = 1.0f - 2.0f / (e + 1.0f);
        float cc = t / fmaxf(sn, EPSc);
        float sx2 = cc * cc * sn2;             // == sum(xd^2)
        float yd = 2.0f * cc * S / (1.0f - sx2);
        out[(size_t)(seg * 16 + j) * Mc + m] = yd;
    }
}

// ---------------------------------------------------------------------------
extern "C" void kernel_launch(void* const* d_in, const int* in_sizes, int n_in,
                              void* d_out, int out_size, void* d_ws, size_t ws_size,
                              hipStream_t stream) {
    const float* dgm     = (const float*)d_in[0];   // (B, N, 17)
    const float* theta   = (const float*)d_in[1];   // (K, M)
    const float* class_w = (const float*)d_in[2];   // (H,)
    int H = in_sizes[2];

    float* P   = (float*)d_ws;                      // 1024 x 128 floats = 512 KB
    float* out = (float*)d_out;

    k_T<<<Bc * NKQ * NCH, 256, 0, stream>>>(dgm, theta, class_w, P, H);
    k_scan<<<1, 1024, 0, stream>>>(P, out);
}